// Round 22
// baseline (71.753 us; speedup 1.0000x reference)
//
#include <hip/hip_runtime.h>
#include <stdint.h>

// Chamfer L1, B=4, N=M=8192, 3-D points — SYMMETRIC single-pass, FP32.
// R22 = R18 skeleton (verified fastest) with the ARITHMETIC swapped:
// v_sad_u16 is QUARTER-RATE (8 cyc — refit of R8 busy-time); fp32 L1 is
// 3x v_sub_f32 + 2x v_add_f32 with FREE |x| source modifiers = 5 full-rate
// ops (10 cyc) per pair vs 16. Ring floor 30.7 -> 21.3 us. Also EXACT
// (no quantization): matches np's (|dx|+|dy|)+|dz| op order bit-for-bit.
// Skeleton identical to R18: prep packs SoA (wsx/wsy/wsz) + inits wsmin;
// wave tile = 128 preds x 256 targets, 4 groups of 16 lanes, NP=8 preds
// stationary, NT=4 targets rotating via in-place DPP row_ror:1; block's
// 4 waves share one tblock -> bwd mins LDS-combined; fp32 mins folded
// via uint atomicMin on positive-float bit patterns. 2048 blocks, 8 w/SIMD.

#define BATCH    4
#define NPTS     8192
#define NP       8
#define NT       4
#define NPTS_TOT (2 * BATCH * NPTS)   // 65536

static __device__ __forceinline__ float min3_f32(float a, float b, float c) {
    float d;
    asm("v_min3_f32 %0, %1, %2, %3" : "=v"(d) : "v"(a), "v"(b), "v"(c));
    return d;
}

static __device__ __forceinline__ uint32_t umin32(uint32_t a, uint32_t b) {
    return a < b ? a : b;
}

// in-place rotate within each 16-lane row: lane l receives lane (l+1)&15
static __device__ __forceinline__ float rot16f(float v) {
    int r = __builtin_amdgcn_update_dpp(__float_as_int(v), __float_as_int(v),
                                        0x121, 0xF, 0xF, false);
    return __int_as_float(r);
}

// L1 distance with free abs modifiers: 3 sub + 2 add (abs on consumers)
static __device__ __forceinline__ float l1dist(float tx, float ty, float tz,
                                               float qx, float qy, float qz) {
    float ax = tx - qx, ay = ty - qy, az = tz - qz;
    return (fabsf(ax) + fabsf(ay)) + fabsf(az);
}

// ws layout: [0, 256K):     wsmin (64K u32: [dir 0..1][batch 0..3][8192])
//            [256K, 512K):  wsx (65536 f32)   [512K, 768K): wsy
//            [768K, 1M):    wsz

__global__ __launch_bounds__(256) void chamfer_prep_kernel(
    const float* __restrict__ pred, const float* __restrict__ target,
    uint32_t* __restrict__ wsmin, float* __restrict__ wsx,
    float* __restrict__ wsy, float* __restrict__ wsz,
    float* __restrict__ out)
{
    const int tid = blockIdx.x * 256 + threadIdx.x;   // 0..65535
    if (tid == 0) out[0] = 0.0f;
    wsmin[tid] = 0xFFFFFFFFu;
    const float* src = (tid < NPTS_TOT / 2)
                     ? pred + (size_t)tid * 3
                     : target + (size_t)(tid - NPTS_TOT / 2) * 3;
    wsx[tid] = src[0];  wsy[tid] = src[1];  wsz[tid] = src[2];
}

__global__ __launch_bounds__(256, 8) void chamfer_sym_kernel(
    const float* __restrict__ wsx, const float* __restrict__ wsy,
    const float* __restrict__ wsz, uint32_t* __restrict__ wsmin)
{
    __shared__ uint32_t bacc[256];   // block-combined bwd mins (float bits)

    const int t    = threadIdx.x;
    const int wid  = t >> 6;
    const int lane = t & 63;
    const int g16  = lane >> 4;
    const int l16  = lane & 15;

    // global wave-tile id: [0, 8192). Block's 4 waves: SAME tblock,
    // 4 consecutive pblocks (enables LDS combine of bwd mins).
    const int tid    = blockIdx.x * 4 + wid;
    const int b      = tid >> 11;          // batch 0..3
    const int rest   = tid & 2047;
    const int tblock = rest >> 6;          // 0..31  (256 targets each)
    const int pblock = rest & 63;          // 0..63  (128 preds each)

    const int pb = pblock * 128;
    const int tb = tblock * 256;
    const int qoff = b * NPTS + pb;                        // + k*16 + l16
    const int toff = NPTS_TOT / 2 + b * NPTS + tb + g16 * 64;  // + m*16 + l16

    bacc[t] = 0xFFFFFFFFu;
    __syncthreads();

    // stationary preds + row accs
    float qx[NP], qy[NP], qz[NP], rowacc[NP];
    #pragma unroll
    for (int k = 0; k < NP; ++k) {
        int i = qoff + k * 16 + l16;
        qx[k] = wsx[i];  qy[k] = wsy[i];  qz[k] = wsz[i];
        rowacc[k] = 1e30f;
    }

    // rotating targets + col accs (group owns 64 distinct targets)
    float tx[NT], ty[NT], tz[NT], colacc[NT];
    #pragma unroll
    for (int m = 0; m < NT; ++m) {
        int i = toff + m * 16 + l16;
        tx[m] = wsx[i];  ty[m] = wsy[i];  tz[m] = wsz[i];
        colacc[m] = 1e30f;
    }

    // 16-round ring: NP x NT pairs per round, both accs updated, then
    // targets+colaccs rotate one lane; after 16 rounds data is home.
    #pragma unroll 4
    for (int r = 0; r < 16; ++r) {
        #pragma unroll
        for (int kk = 0; kk < NP; kk += 2) {
            float d0[NT], d1[NT];
            #pragma unroll
            for (int m = 0; m < NT; ++m) {
                d0[m] = l1dist(tx[m], ty[m], tz[m], qx[kk],     qy[kk],     qz[kk]);
                d1[m] = l1dist(tx[m], ty[m], tz[m], qx[kk + 1], qy[kk + 1], qz[kk + 1]);
            }
            rowacc[kk]     = min3_f32(d0[0], d0[1], min3_f32(d0[2], d0[3], rowacc[kk]));
            rowacc[kk + 1] = min3_f32(d1[0], d1[1], min3_f32(d1[2], d1[3], rowacc[kk + 1]));
            #pragma unroll
            for (int m = 0; m < NT; ++m)
                colacc[m] = min3_f32(d0[m], d1[m], colacc[m]);
        }
        #pragma unroll
        for (int m = 0; m < NT; ++m) {
            tx[m] = rot16f(tx[m]);
            ty[m] = rot16f(ty[m]);
            tz[m] = rot16f(tz[m]);
            colacc[m] = rot16f(colacc[m]);
        }
    }

    // forward (pred as query): min across the 4 duplicate groups; group
    // (k>>1) issues the atomic for pred row k. Positive-float bits are
    // monotonic under uint compare -> uint atomicMin is exact.
    uint32_t* fmin = wsmin + (size_t)b * NPTS;
    #pragma unroll
    for (int k = 0; k < NP; ++k) {
        float v = rowacc[k];
        v = fminf(v, __int_as_float(__shfl_xor(__float_as_int(v), 16)));
        v = fminf(v, __int_as_float(__shfl_xor(__float_as_int(v), 32)));
        if (g16 == (k >> 1))
            atomicMin(&fmin[pb + k * 16 + l16], __float_as_uint(v));
    }

    // backward (target as query): combine the block's 4 waves in LDS,
    // then one coalesced global atomic per target (256 per block).
    #pragma unroll
    for (int m = 0; m < NT; ++m)
        atomicMin(&bacc[g16 * 64 + m * 16 + l16], __float_as_uint(colacc[m]));
    __syncthreads();

    uint32_t* bmin = wsmin + (size_t)(BATCH + b) * NPTS;
    atomicMin(&bmin[tb + t], bacc[t]);
}

__global__ __launch_bounds__(256) void chamfer_reduce_kernel(
    const uint32_t* __restrict__ wsmin, float* __restrict__ out)
{
    const int t = threadIdx.x;
    const uint4* p = reinterpret_cast<const uint4*>(wsmin);   // 16384 uint4
    float s = 0.0f;
    #pragma unroll
    for (int i = 0; i < 4; ++i) {
        uint4 v = p[blockIdx.x * 1024 + i * 256 + t];
        s += __uint_as_float(v.x) + __uint_as_float(v.y)
           + __uint_as_float(v.z) + __uint_as_float(v.w);
    }
    #pragma unroll
    for (int off = 32; off > 0; off >>= 1)
        s += __shfl_down(s, off);
    if ((t & 63) == 0)
        atomicAdd(out, s * (1.0f / (float)BATCH));
}

extern "C" void kernel_launch(void* const* d_in, const int* in_sizes, int n_in,
                              void* d_out, int out_size, void* d_ws, size_t ws_size,
                              hipStream_t stream) {
    const float* pred   = (const float*)d_in[0];
    const float* target = (const float*)d_in[1];
    float* out = (float*)d_out;
    uint32_t* wsmin = (uint32_t*)d_ws;                        // 256 KiB
    float*    wsx   = (float*)((char*)d_ws + 256 * 1024);     // 256 KiB
    float*    wsy   = (float*)((char*)d_ws + 512 * 1024);     // 256 KiB
    float*    wsz   = (float*)((char*)d_ws + 768 * 1024);     // 256 KiB

    chamfer_prep_kernel<<<NPTS_TOT / 256, 256, 0, stream>>>(
        pred, target, wsmin, wsx, wsy, wsz, out);

    // 8192 wave-tiles, 4 waves/block -> 2048 blocks (8/CU, 8 waves/SIMD)
    chamfer_sym_kernel<<<2048, 256, 0, stream>>>(wsx, wsy, wsz, wsmin);

    chamfer_reduce_kernel<<<16, 256, 0, stream>>>(wsmin, out);
}

// Round 23
// 49.608 us; speedup vs baseline: 1.4464x; 1.4464x over previous
//
#include <hip/hip_runtime.h>
#include <stdint.h>

// Chamfer L1, B=4, N=M=8192, 3-D points — SYMMETRIC single-pass, FP32.
// R23 = R22 with launch_bounds(256,6) (85-VGPR cap) instead of (256,8)
// (64-cap). R22 exposed the session-long spill trigger: when live state
// (~56 regs for the fp32 ring) exceeds the launch-bounds VGPR cap, the
// allocator collapses to ~30 regs and scratches EVERYTHING (VGPR=32,
// FETCH 39MB/WRITE 85MB per dispatch). 6 waves/SIMD of dense VALU still
// saturates issue; total work-cycles unchanged (~22 us ring floor).
// Ring: fp32 L1 = 3x v_sub_f32 + 2x v_add_f32 (free |x| modifiers) +
// v_min3_f32 — 2x cheaper than quarter-rate v_sad_u16, and EXACT
// (matches np op order (|dx|+|dy|)+|dz|; no quantization).
// Skeleton = R18: prep packs SoA + inits wsmin; 128 preds x 256 targets
// per wave-tile; NP=8 stationary, NT=4 rotating via in-place DPP
// row_ror:1; block's 4 waves share a tblock -> bwd LDS-combine; uint
// atomicMin on positive-float bits. 2048 blocks.

#define BATCH    4
#define NPTS     8192
#define NP       8
#define NT       4
#define NPTS_TOT (2 * BATCH * NPTS)   // 65536

static __device__ __forceinline__ float min3_f32(float a, float b, float c) {
    float d;
    asm("v_min3_f32 %0, %1, %2, %3" : "=v"(d) : "v"(a), "v"(b), "v"(c));
    return d;
}

// in-place rotate within each 16-lane row: lane l receives lane (l+1)&15
static __device__ __forceinline__ float rot16f(float v) {
    int r = __builtin_amdgcn_update_dpp(__float_as_int(v), __float_as_int(v),
                                        0x121, 0xF, 0xF, false);
    return __int_as_float(r);
}

// L1 distance with free abs modifiers: 3 sub + 2 add (abs on consumers)
static __device__ __forceinline__ float l1dist(float tx, float ty, float tz,
                                               float qx, float qy, float qz) {
    float ax = tx - qx, ay = ty - qy, az = tz - qz;
    return (fabsf(ax) + fabsf(ay)) + fabsf(az);
}

// ws layout: [0, 256K):     wsmin (64K u32: [dir 0..1][batch 0..3][8192])
//            [256K, 512K):  wsx (65536 f32)   [512K, 768K): wsy
//            [768K, 1M):    wsz

__global__ __launch_bounds__(256) void chamfer_prep_kernel(
    const float* __restrict__ pred, const float* __restrict__ target,
    uint32_t* __restrict__ wsmin, float* __restrict__ wsx,
    float* __restrict__ wsy, float* __restrict__ wsz,
    float* __restrict__ out)
{
    const int tid = blockIdx.x * 256 + threadIdx.x;   // 0..65535
    if (tid == 0) out[0] = 0.0f;
    wsmin[tid] = 0xFFFFFFFFu;
    const float* src = (tid < NPTS_TOT / 2)
                     ? pred + (size_t)tid * 3
                     : target + (size_t)(tid - NPTS_TOT / 2) * 3;
    wsx[tid] = src[0];  wsy[tid] = src[1];  wsz[tid] = src[2];
}

__global__ __launch_bounds__(256, 6) void chamfer_sym_kernel(
    const float* __restrict__ wsx, const float* __restrict__ wsy,
    const float* __restrict__ wsz, uint32_t* __restrict__ wsmin)
{
    __shared__ uint32_t bacc[256];   // block-combined bwd mins (float bits)

    const int t    = threadIdx.x;
    const int wid  = t >> 6;
    const int lane = t & 63;
    const int g16  = lane >> 4;
    const int l16  = lane & 15;

    // global wave-tile id: [0, 8192). Block's 4 waves: SAME tblock,
    // 4 consecutive pblocks (enables LDS combine of bwd mins).
    const int tid    = blockIdx.x * 4 + wid;
    const int b      = tid >> 11;          // batch 0..3
    const int rest   = tid & 2047;
    const int tblock = rest >> 6;          // 0..31  (256 targets each)
    const int pblock = rest & 63;          // 0..63  (128 preds each)

    const int pb = pblock * 128;
    const int tb = tblock * 256;
    const int qoff = b * NPTS + pb;                            // + k*16 + l16
    const int toff = NPTS_TOT / 2 + b * NPTS + tb + g16 * 64;  // + m*16 + l16

    bacc[t] = 0xFFFFFFFFu;
    __syncthreads();

    // stationary preds + row accs
    float qx[NP], qy[NP], qz[NP], rowacc[NP];
    #pragma unroll
    for (int k = 0; k < NP; ++k) {
        int i = qoff + k * 16 + l16;
        qx[k] = wsx[i];  qy[k] = wsy[i];  qz[k] = wsz[i];
        rowacc[k] = 1e30f;
    }

    // rotating targets + col accs (group owns 64 distinct targets)
    float tx[NT], ty[NT], tz[NT], colacc[NT];
    #pragma unroll
    for (int m = 0; m < NT; ++m) {
        int i = toff + m * 16 + l16;
        tx[m] = wsx[i];  ty[m] = wsy[i];  tz[m] = wsz[i];
        colacc[m] = 1e30f;
    }

    // 16-round ring: NP x NT pairs per round, both accs updated, then
    // targets+colaccs rotate one lane; after 16 rounds data is home.
    #pragma unroll 4
    for (int r = 0; r < 16; ++r) {
        #pragma unroll
        for (int kk = 0; kk < NP; kk += 2) {
            float d0[NT], d1[NT];
            #pragma unroll
            for (int m = 0; m < NT; ++m) {
                d0[m] = l1dist(tx[m], ty[m], tz[m], qx[kk],     qy[kk],     qz[kk]);
                d1[m] = l1dist(tx[m], ty[m], tz[m], qx[kk + 1], qy[kk + 1], qz[kk + 1]);
            }
            rowacc[kk]     = min3_f32(d0[0], d0[1], min3_f32(d0[2], d0[3], rowacc[kk]));
            rowacc[kk + 1] = min3_f32(d1[0], d1[1], min3_f32(d1[2], d1[3], rowacc[kk + 1]));
            #pragma unroll
            for (int m = 0; m < NT; ++m)
                colacc[m] = min3_f32(d0[m], d1[m], colacc[m]);
        }
        #pragma unroll
        for (int m = 0; m < NT; ++m) {
            tx[m] = rot16f(tx[m]);
            ty[m] = rot16f(ty[m]);
            tz[m] = rot16f(tz[m]);
            colacc[m] = rot16f(colacc[m]);
        }
    }

    // forward (pred as query): min across the 4 duplicate groups; group
    // (k>>1) issues the atomic for pred row k. Positive-float bits are
    // monotonic under uint compare -> uint atomicMin is exact.
    uint32_t* fmin = wsmin + (size_t)b * NPTS;
    #pragma unroll
    for (int k = 0; k < NP; ++k) {
        float v = rowacc[k];
        v = fminf(v, __int_as_float(__shfl_xor(__float_as_int(v), 16)));
        v = fminf(v, __int_as_float(__shfl_xor(__float_as_int(v), 32)));
        if (g16 == (k >> 1))
            atomicMin(&fmin[pb + k * 16 + l16], __float_as_uint(v));
    }

    // backward (target as query): combine the block's 4 waves in LDS,
    // then one coalesced global atomic per target (256 per block).
    #pragma unroll
    for (int m = 0; m < NT; ++m)
        atomicMin(&bacc[g16 * 64 + m * 16 + l16], __float_as_uint(colacc[m]));
    __syncthreads();

    uint32_t* bmin = wsmin + (size_t)(BATCH + b) * NPTS;
    atomicMin(&bmin[tb + t], bacc[t]);
}

__global__ __launch_bounds__(256) void chamfer_reduce_kernel(
    const uint32_t* __restrict__ wsmin, float* __restrict__ out)
{
    const int t = threadIdx.x;
    const uint4* p = reinterpret_cast<const uint4*>(wsmin);   // 16384 uint4
    float s = 0.0f;
    #pragma unroll
    for (int i = 0; i < 4; ++i) {
        uint4 v = p[blockIdx.x * 1024 + i * 256 + t];
        s += __uint_as_float(v.x) + __uint_as_float(v.y)
           + __uint_as_float(v.z) + __uint_as_float(v.w);
    }
    #pragma unroll
    for (int off = 32; off > 0; off >>= 1)
        s += __shfl_down(s, off);
    if ((t & 63) == 0)
        atomicAdd(out, s * (1.0f / (float)BATCH));
}

extern "C" void kernel_launch(void* const* d_in, const int* in_sizes, int n_in,
                              void* d_out, int out_size, void* d_ws, size_t ws_size,
                              hipStream_t stream) {
    const float* pred   = (const float*)d_in[0];
    const float* target = (const float*)d_in[1];
    float* out = (float*)d_out;
    uint32_t* wsmin = (uint32_t*)d_ws;                        // 256 KiB
    float*    wsx   = (float*)((char*)d_ws + 256 * 1024);     // 256 KiB
    float*    wsy   = (float*)((char*)d_ws + 512 * 1024);     // 256 KiB
    float*    wsz   = (float*)((char*)d_ws + 768 * 1024);     // 256 KiB

    chamfer_prep_kernel<<<NPTS_TOT / 256, 256, 0, stream>>>(
        pred, target, wsmin, wsx, wsy, wsz, out);

    // 8192 wave-tiles, 4 waves/block -> 2048 blocks (6 waves/SIMD cap)
    chamfer_sym_kernel<<<2048, 256, 0, stream>>>(wsx, wsy, wsz, wsmin);

    chamfer_reduce_kernel<<<16, 256, 0, stream>>>(wsmin, out);
}